// Round 1
// baseline (9059.237 us; speedup 1.0000x reference)
//
#include <hip/hip_runtime.h>

namespace {

constexpr int T_STEPS = 2000;
constexpr int BATCH   = 512;
constexpr int DIN     = 85;
constexpr int HID     = 256;
constexpr int DOUT    = 33;
constexpr int NWG     = 32;   // 16 batch rows per workgroup
constexpr int NTHR    = 512;  // 8 waves

typedef float f32x4  __attribute__((ext_vector_type(4)));
typedef short bf16x8 __attribute__((ext_vector_type(8)));

__device__ __forceinline__ short f2bf(float f) {
    union { float f; unsigned u; } v; v.f = f;
    unsigned r = v.u + 0x7fffu + ((v.u >> 16) & 1u);   // RNE
    return (short)(r >> 16);
}

__device__ __forceinline__ float softplus_(float x) {
    return fmaxf(x, 0.f) + log1pf(expf(-fabsf(x)));
}
__device__ __forceinline__ float sigmoid_(float x) {
    return 1.f / (1.f + expf(-x));
}

// XOR-swizzled LDS byte offsets (G4: spread row-major columns across banks)
__device__ __forceinline__ int hswz(int row, int byteInRow) {
    return row * 512 + (byteInRow ^ ((row & 7) << 4));
}
__device__ __forceinline__ int xswz(int row, int byteInRow) {
    return row * 256 + (byteInRow ^ ((row & 7) << 4));
}

#define MFMA16(a, b, c) __builtin_amdgcn_mfma_f32_16x16x32_bf16((a), (b), (c), 0, 0, 0)

__global__ __launch_bounds__(NTHR, 2) void rnn_fused(
    const float* __restrict__ x, const float* __restrict__ y,
    const float* __restrict__ cmask, const float* __restrict__ weight,
    const float* __restrict__ bias, const float* __restrict__ wout,
    const float* __restrict__ bout, float* __restrict__ yhat,
    float* __restrict__ cost)
{
    __shared__ __align__(16) unsigned short h_lds[2][16 * 256]; // 16 KB, 512B/row, swizzled
    __shared__ __align__(16) unsigned short x_lds[2][16 * 128]; // 8 KB, 256B/row, swizzled (k padded to 96)
    __shared__ float slab[6][256];                              // proj partials
    __shared__ float redbuf[8];

    const int tid  = threadIdx.x;
    const int lane = tid & 63;
    const int wv   = tid >> 6;   // 0..7
    const int lg   = lane >> 4;  // 0..3
    const int li   = lane & 15;
    const int r0   = blockIdx.x * 16;  // batch-row base
    const int cw   = wv * 32;          // this wave's H-column base

    // ---------------- init: weight fragments into registers ----------------
    // B-frag mapping (16x16x32): col = lane&15, k = 8*(lane>>4)+j
    bf16x8 wrec[2][8];
    #pragma unroll
    for (int ct = 0; ct < 2; ++ct) {
        const int col = cw + 16 * ct + li;
        #pragma unroll
        for (int kk = 0; kk < 8; ++kk) {
            bf16x8 f;
            #pragma unroll
            for (int j = 0; j < 8; ++j) {
                const int k = 32 * kk + 8 * lg + j;
                f[j] = f2bf(weight[(85 + k) * HID + col]);
            }
            wrec[ct][kk] = f;
        }
    }
    bf16x8 win[2][3];
    #pragma unroll
    for (int ct = 0; ct < 2; ++ct) {
        const int col = cw + 16 * ct + li;
        #pragma unroll
        for (int kk = 0; kk < 3; ++kk) {
            bf16x8 f;
            #pragma unroll
            for (int j = 0; j < 8; ++j) {
                const int k = 32 * kk + 8 * lg + j;
                f[j] = (k < DIN) ? f2bf(weight[k * HID + col]) : (short)0;
            }
            win[ct][kk] = f;
        }
    }
    const int ptile = wv >> 1;   // proj col-tile (0..2) for waves 0..5
    const int pkh   = wv & 1;    // proj k-half
    bf16x8 wo[4];
    #pragma unroll
    for (int kk = 0; kk < 4; ++kk) {
        bf16x8 f;
        const int c = 16 * ptile + li;
        #pragma unroll
        for (int j = 0; j < 8; ++j) {
            const int kfull = 32 * (4 * pkh + kk) + 8 * lg + j;
            f[j] = (wv < 6 && c < DOUT) ? f2bf(wout[kfull * DOUT + c]) : (short)0;
        }
        wo[kk] = f;
    }
    const float bias_c0 = bias[cw + li];
    const float bias_c1 = bias[cw + 16 + li];

    // ---------------- finalize-slot mapping (t-invariant) ----------------
    const int s0 = tid;                 // 0..511
    const int s1 = tid + NTHR;          // 512..1023
    const bool has1 = (s1 < 16 * DOUT); // 528 total slots
    const int row0 = s0 / DOUT, col0 = s0 % DOUT;
    const int row1 = has1 ? s1 / DOUT : 0, col1 = has1 ? s1 % DOUT : 0;
    const float bo0 = bout[col0];
    const float bo1 = bout[col1];
    const int obase0 = (r0 + row0) * DOUT + col0;
    const int obase1 = (r0 + row1) * DOUT + col1;

    // ---------------- x staging mapping ----------------
    int xrow[3], xdd[3], xoff[3];
    bool xval[3];
    #pragma unroll
    for (int i = 0; i < 3; ++i) {
        const int s = tid + NTHR * i;   // 0..1535 = 16 rows * 96 padded k
        xrow[i] = s / 96;
        xdd[i]  = s % 96;
        xval[i] = (xdd[i] < DIN);
        xoff[i] = (r0 + xrow[i]) * (T_STEPS * DIN) + xdd[i];
    }

    // zero h buffers (h0 = 0)
    for (int i = tid; i < 2 * 16 * 256; i += NTHR)
        ((unsigned short*)h_lds)[i] = 0;

    // stage x for t = 0
    {
        #pragma unroll
        for (int i = 0; i < 3; ++i) {
            const float v = xval[i] ? x[xoff[i]] : 0.f;
            *(unsigned short*)((char*)x_lds[0] + xswz(xrow[i], xdd[i] * 2)) = (unsigned short)f2bf(v);
        }
    }

    f32x4 hreg[2] = {{0.f, 0.f, 0.f, 0.f}, {0.f, 0.f, 0.f, 0.f}};
    float costacc = 0.f;
    __syncthreads();

    // ---------------- main sequential loop ----------------
    for (int t = 0; t < T_STEPS; ++t) {
        const int cur = t & 1, nxt = cur ^ 1;
        const char* hcur = (const char*)h_lds[cur];
        char*       hnxt = (char*)h_lds[nxt];
        const char* xcur = (const char*)x_lds[cur];
        char*       xnxt = (char*)x_lds[nxt];

        // A: issue y / c_mask loads for this step (used in finalize)
        const int idx0 = t * (BATCH * DOUT) + obase0;
        const float yv0 = y[idx0];
        const float mv0 = cmask[idx0];
        int idx1 = 0; float yv1 = 0.f, mv1 = 0.f;
        if (has1) { idx1 = t * (BATCH * DOUT) + obase1; yv1 = y[idx1]; mv1 = cmask[idx1]; }

        // B: issue x loads for t+1 (prefetch; hides HBM latency under MFMA)
        const bool havex = (t + 1 < T_STEPS);
        float xv[3] = {0.f, 0.f, 0.f};
        if (havex) {
            const int xt = (t + 1) * DIN;
            #pragma unroll
            for (int i = 0; i < 3; ++i)
                xv[i] = xval[i] ? x[xoff[i] + xt] : 0.f;
        }

        // C: gate = h @ w_rec + x @ w_in   (acc pre-seeded with bias)
        f32x4 acc0 = {bias_c0, bias_c0, bias_c0, bias_c0};
        f32x4 acc1 = {bias_c1, bias_c1, bias_c1, bias_c1};
        #pragma unroll
        for (int kk = 0; kk < 8; ++kk) {
            const bf16x8 a = *(const bf16x8*)(hcur + hswz(li, (32 * kk + 8 * lg) * 2));
            acc0 = MFMA16(a, wrec[0][kk], acc0);
            acc1 = MFMA16(a, wrec[1][kk], acc1);
        }
        #pragma unroll
        for (int kk = 0; kk < 3; ++kk) {
            const bf16x8 a = *(const bf16x8*)(xcur + xswz(li, (32 * kk + 8 * lg) * 2));
            acc0 = MFMA16(a, win[0][kk], acc0);
            acc1 = MFMA16(a, win[1][kk], acc1);
        }

        // D: softplus + leaky update; write h_new (bf16) to next buffer
        // C/D frag: col = lane&15, row = 4*(lane>>4)+reg  [HW-verified]
        #pragma unroll
        for (int r = 0; r < 4; ++r) {
            const int grow = lg * 4 + r;
            {
                const float hn = 0.8f * hreg[0][r] + 0.2f * softplus_(acc0[r]);
                hreg[0][r] = hn;
                const int gcol = cw + li;
                *(unsigned short*)(hnxt + hswz(grow, gcol * 2)) = (unsigned short)f2bf(hn);
            }
            {
                const float hn = 0.8f * hreg[1][r] + 0.2f * softplus_(acc1[r]);
                hreg[1][r] = hn;
                const int gcol = cw + 16 + li;
                *(unsigned short*)(hnxt + hswz(grow, gcol * 2)) = (unsigned short)f2bf(hn);
            }
        }

        // E: commit prefetched x_{t+1} into next x buffer
        if (havex) {
            #pragma unroll
            for (int i = 0; i < 3; ++i)
                *(unsigned short*)(xnxt + xswz(xrow[i], xdd[i] * 2)) = (unsigned short)f2bf(xv[i]);
        }

        __syncthreads();   // h_new + x_{t+1} visible

        // G: projection partials: z = h_new @ w_out (waves 0..5, 2-way K split)
        if (wv < 6) {
            f32x4 ap = {0.f, 0.f, 0.f, 0.f};
            #pragma unroll
            for (int kk = 0; kk < 4; ++kk) {
                const bf16x8 a = *(const bf16x8*)((const char*)hnxt +
                                   hswz(li, (32 * (4 * pkh + kk) + 8 * lg) * 2));
                ap = MFMA16(a, wo[kk], ap);
            }
            #pragma unroll
            for (int r = 0; r < 4; ++r)
                slab[wv][(lg * 4 + r) * 16 + li] = ap[r];
        }

        __syncthreads();   // partials visible

        // I: finalize: sigmoid, store y_hat, accumulate masked sq-err
        {
            const int tile = col0 >> 4, cc = col0 & 15;
            const float z = slab[2 * tile][row0 * 16 + cc] +
                            slab[2 * tile + 1][row0 * 16 + cc] + bo0;
            const float s = sigmoid_(z);
            yhat[idx0] = s;
            const float d = (yv0 - s) * mv0;
            costacc += d * d;
        }
        if (has1) {
            const int tile = col1 >> 4, cc = col1 & 15;
            const float z = slab[2 * tile][row1 * 16 + cc] +
                            slab[2 * tile + 1][row1 * 16 + cc] + bo1;
            const float s = sigmoid_(z);
            yhat[idx1] = s;
            const float d = (yv1 - s) * mv1;
            costacc += d * d;
        }
        // slab reuse next step is ordered by the first barrier of the next iter
    }

    // ---------------- cost reduction ----------------
    #pragma unroll
    for (int o = 32; o > 0; o >>= 1)
        costacc += __shfl_down(costacc, o, 64);
    if (lane == 0) redbuf[wv] = costacc;
    __syncthreads();
    if (tid == 0) {
        float s = 0.f;
        #pragma unroll
        for (int i = 0; i < 8; ++i) s += redbuf[i];
        atomicAdd(cost, s * (1.0f / (float)((long)T_STEPS * BATCH * DOUT)));
    }
}

} // namespace

extern "C" void kernel_launch(void* const* d_in, const int* in_sizes, int n_in,
                              void* d_out, int out_size, void* d_ws, size_t ws_size,
                              hipStream_t stream) {
    const float* x      = (const float*)d_in[0];
    const float* y      = (const float*)d_in[1];
    const float* cmask  = (const float*)d_in[2];
    const float* weight = (const float*)d_in[3];
    const float* bias   = (const float*)d_in[4];
    const float* wout   = (const float*)d_in[5];
    const float* bout   = (const float*)d_in[6];

    float* yhat = (float*)d_out;
    float* cost = yhat + (size_t)T_STEPS * BATCH * DOUT;

    // zero the scalar-cost accumulator (capture-legal memset node)
    hipMemsetAsync(cost, 0, sizeof(float), stream);

    rnn_fused<<<dim3(NWG), dim3(NTHR), 0, stream>>>(
        x, y, cmask, weight, bias, wout, bout, yhat, cost);
}

// Round 2
// 4609.852 us; speedup vs baseline: 1.9652x; 1.9652x over previous
//
#include <hip/hip_runtime.h>

namespace {

constexpr int T_STEPS = 2000;
constexpr int BATCH   = 512;
constexpr int DIN     = 85;
constexpr int HID     = 256;
constexpr int DOUT    = 33;
constexpr int NWG     = 32;   // 16 batch rows per workgroup
constexpr int NTHR    = 256;  // 4 waves, 64 gate cols each

typedef float f32x4  __attribute__((ext_vector_type(4)));
typedef short bf16x8 __attribute__((ext_vector_type(8)));
typedef unsigned short ushort_t;

__device__ __forceinline__ short f2bf(float f) {
    union { float f; unsigned u; } v; v.f = f;
    unsigned r = v.u + 0x7fffu + ((v.u >> 16) & 1u);   // RNE
    return (short)(r >> 16);
}
// packed f32x2 -> bf16x2 (RNE), 1 instruction
__device__ __forceinline__ unsigned cvtpk(float lo, float hi) {
    unsigned r;
    asm("v_cvt_pk_bf16_f32 %0, %1, %2" : "=v"(r) : "v"(lo), "v"(hi));
    return r;
}
__device__ __forceinline__ float fast_rcp(float x) {
    float r; asm("v_rcp_f32 %0, %1" : "=v"(r) : "v"(x)); return r;
}
__device__ __forceinline__ float softplus_(float x) {
    float e = __expf(-fabsf(x));
    return fmaxf(x, 0.f) + __logf(1.f + e);
}
__device__ __forceinline__ float sigmoid_(float x) {
    return fast_rcp(1.f + __expf(-x));
}
// h K-slot permutation: slot(col) = (col&15)*16 + (col>>6)*4 + ((col>>4)&3)
// inverse: col(slot) = ((slot>>2)&3)*64 + (slot&3)*16 + (slot>>4)
__device__ __forceinline__ int kcol_of_slot(int s) {
    return ((s >> 2) & 3) * 64 + (s & 3) * 16 + (s >> 4);
}

#define MFMA16(a, b, c) __builtin_amdgcn_mfma_f32_16x16x32_bf16((a), (b), (c), 0, 0, 0)

__global__ __launch_bounds__(NTHR, 1) void rnn_fused(
    const float* __restrict__ x, const float* __restrict__ y,
    const float* __restrict__ cmask, const float* __restrict__ weight,
    const float* __restrict__ bias, const float* __restrict__ wout,
    const float* __restrict__ bout, float* __restrict__ yhat,
    float* __restrict__ cost)
{
    // h: [buf][row 16][slot 256] bf16, 512 B/row, XOR-swizzled; slots are permuted K
    // x: [buf][row 16][slot 128] bf16, 256 B/row, XOR-swizzled; natural K (pad 85->96)
    __shared__ __align__(16) ushort_t h_lds[2][16 * 256]; // 16 KB
    __shared__ __align__(16) ushort_t x_lds[2][16 * 128]; // 8 KB
    __shared__ float redbuf[4];

    const int tid  = threadIdx.x;
    const int lane = tid & 63;
    const int wv   = tid >> 6;   // 0..3
    const int lg   = lane >> 4;  // 0..3
    const int li   = lane & 15;
    const int r0   = blockIdx.x * 16;

    // ---------------- weight fragments (registers; K permuted via slots) -------
    bf16x8 wrec[4][8], win[4][3];
    #pragma unroll
    for (int ct = 0; ct < 4; ++ct) {
        const int gcol = wv * 64 + ct * 16 + li;
        #pragma unroll
        for (int kk = 0; kk < 8; ++kk) {
            bf16x8 f;
            #pragma unroll
            for (int j = 0; j < 8; ++j) {
                const int kc = kcol_of_slot(32 * kk + 8 * lg + j);
                f[j] = f2bf(weight[(DIN + kc) * HID + gcol]);
            }
            wrec[ct][kk] = f;
        }
        #pragma unroll
        for (int kk = 0; kk < 3; ++kk) {
            bf16x8 f;
            #pragma unroll
            for (int j = 0; j < 8; ++j) {
                const int k = 32 * kk + 8 * lg + j;   // natural K for x
                f[j] = (k < DIN) ? f2bf(weight[k * HID + gcol]) : (short)0;
            }
            win[ct][kk] = f;
        }
    }
    float biasv[4];
    #pragma unroll
    for (int ct = 0; ct < 4; ++ct) biasv[ct] = bias[wv * 64 + ct * 16 + li];

    // projection fragments (waves 0..2, col tile wv)
    const bool pw     = (wv < 3);
    const int  pcol   = wv * 16 + li;
    const bool pvalid = pw && (pcol < DOUT);
    bf16x8 wo[8];
    #pragma unroll
    for (int kk = 0; kk < 8; ++kk) {
        bf16x8 f;
        #pragma unroll
        for (int j = 0; j < 8; ++j) {
            const int kc = kcol_of_slot(32 * kk + 8 * lg + j);
            f[j] = pvalid ? f2bf(wout[kc * DOUT + pcol]) : (short)0;
        }
        wo[kk] = f;
    }
    const float bo = pvalid ? bout[pcol] : 0.f;
    int obase[4];
    #pragma unroll
    for (int r = 0; r < 4; ++r) obase[r] = (r0 + 4 * lg + r) * DOUT + pcol;

    // ---------------- LDS addresses (loop-invariant) ----------------
    const int swzli = (li & 7) << 4;
    int hA_off[8], xA_off[3], hW_off[4];
    #pragma unroll
    for (int kk = 0; kk < 8; ++kk) hA_off[kk] = li * 512 + ((kk * 64 + lg * 16) ^ swzli);
    #pragma unroll
    for (int kk = 0; kk < 3; ++kk) xA_off[kk] = li * 256 + ((kk * 64 + lg * 16) ^ swzli);
    #pragma unroll
    for (int r = 0; r < 4; ++r) {
        const int row = 4 * lg + r;
        hW_off[r] = row * 512 + ((li * 32 + wv * 8) ^ ((row & 7) << 4));
    }

    // x staging: 16 rows * 48 pairs = 768 pair-slots, 3 per thread
    int xg[3], xW_off[3]; bool v0[3], v1[3];
    #pragma unroll
    for (int i = 0; i < 3; ++i) {
        const int p   = tid + NTHR * i;
        const int row = p / 48;
        const int d0  = (p % 48) * 2;
        v0[i] = (d0 < DIN);
        v1[i] = (d0 + 1 < DIN);
        xg[i] = (r0 + row) * (T_STEPS * DIN) + d0;
        xW_off[i] = row * 256 + ((d0 * 2) ^ ((row & 7) << 4));
    }

    // stage x(t=0) into buffer 0
    #pragma unroll
    for (int i = 0; i < 3; ++i) {
        const float a = v0[i] ? x[xg[i]] : 0.f;
        const float b = v1[i] ? x[xg[i] + 1] : 0.f;
        *(unsigned*)((char*)x_lds[0] + xW_off[i]) = cvtpk(a, b);
    }
    __syncthreads();

    bf16x8 hA[8];
    #pragma unroll
    for (int kk = 0; kk < 8; ++kk) hA[kk] = (bf16x8)0;   // h0 = 0
    f32x4 hr[4] = {{0,0,0,0},{0,0,0,0},{0,0,0,0},{0,0,0,0}};
    float costacc = 0.f;

    // ---------------- main sequential loop: ONE barrier per step ----------------
    for (int t = 0; t < T_STEPS; ++t) {
        const int nb = (t & 1) ^ 1;
        const char* xcur = (const char*)x_lds[t & 1];
        char*       xnxt = (char*)x_lds[nb];
        char*       hnxt = (char*)h_lds[nb];

        // prefetch x(t+1) (HBM latency hides under gate MFMA)
        const bool havex = (t + 1 < T_STEPS);
        float xa[3], xb_[3];
        if (havex) {
            const int toff = (t + 1) * DIN;
            #pragma unroll
            for (int i = 0; i < 3; ++i) {
                xa[i]  = v0[i] ? x[xg[i] + toff] : 0.f;
                xb_[i] = v1[i] ? x[xg[i] + toff + 1] : 0.f;
            }
        }
        // prefetch y/c_mask for this step (used after barrier)
        float yv[4], mv[4]; int oidx[4];
        if (pvalid) {
            #pragma unroll
            for (int r = 0; r < 4; ++r) {
                oidx[r] = t * (BATCH * DOUT) + obase[r];
                yv[r] = y[oidx[r]];
                mv[r] = cmask[oidx[r]];
            }
        }

        // gate = h @ w_rec + x @ w_in + bias   (4 independent MFMA chains)
        f32x4 acc[4];
        #pragma unroll
        for (int ct = 0; ct < 4; ++ct)
            acc[ct] = (f32x4){biasv[ct], biasv[ct], biasv[ct], biasv[ct]};
        #pragma unroll
        for (int kk = 0; kk < 8; ++kk) {
            const bf16x8 a = hA[kk];
            acc[0] = MFMA16(a, wrec[0][kk], acc[0]);
            acc[1] = MFMA16(a, wrec[1][kk], acc[1]);
            acc[2] = MFMA16(a, wrec[2][kk], acc[2]);
            acc[3] = MFMA16(a, wrec[3][kk], acc[3]);
        }
        #pragma unroll
        for (int kk = 0; kk < 3; ++kk) {
            const bf16x8 a = *(const bf16x8*)(xcur + xA_off[kk]);
            acc[0] = MFMA16(a, win[0][kk], acc[0]);
            acc[1] = MFMA16(a, win[1][kk], acc[1]);
            acc[2] = MFMA16(a, win[2][kk], acc[2]);
            acc[3] = MFMA16(a, win[3][kk], acc[3]);
        }

        // leaky softplus update; pack 4 tile-values -> 4 consecutive slots -> b64
        #pragma unroll
        for (int r = 0; r < 4; ++r) {
            const float h0 = 0.8f * hr[0][r] + 0.2f * softplus_(acc[0][r]);
            const float h1 = 0.8f * hr[1][r] + 0.2f * softplus_(acc[1][r]);
            const float h2 = 0.8f * hr[2][r] + 0.2f * softplus_(acc[2][r]);
            const float h3 = 0.8f * hr[3][r] + 0.2f * softplus_(acc[3][r]);
            hr[0][r] = h0; hr[1][r] = h1; hr[2][r] = h2; hr[3][r] = h3;
            uint2 pk; pk.x = cvtpk(h0, h1); pk.y = cvtpk(h2, h3);
            *(uint2*)(hnxt + hW_off[r]) = pk;
        }
        // commit x(t+1)
        if (havex) {
            #pragma unroll
            for (int i = 0; i < 3; ++i)
                *(unsigned*)(xnxt + xW_off[i]) = cvtpk(xa[i], xb_[i]);
        }

        __syncthreads();   // h_new + x(t+1) visible

        // reload h A-fragments ONCE: used by proj(t) AND gate(t+1)
        #pragma unroll
        for (int kk = 0; kk < 8; ++kk)
            hA[kk] = *(const bf16x8*)((const char*)hnxt + hA_off[kk]);

        // projection + sigmoid + store + cost (waves 0..2, in-register)
        if (pw) {
            f32x4 p0 = {0,0,0,0}, p1 = {0,0,0,0};
            #pragma unroll
            for (int kk = 0; kk < 4; ++kk) p0 = MFMA16(hA[kk], wo[kk], p0);
            #pragma unroll
            for (int kk = 4; kk < 8; ++kk) p1 = MFMA16(hA[kk], wo[kk], p1);
            if (pvalid) {
                #pragma unroll
                for (int r = 0; r < 4; ++r) {
                    const float s = sigmoid_(p0[r] + p1[r] + bo);
                    yhat[oidx[r]] = s;
                    const float d = (yv[r] - s) * mv[r];
                    costacc += d * d;
                }
            }
        }
    }

    // ---------------- cost reduction ----------------
    #pragma unroll
    for (int o = 32; o > 0; o >>= 1)
        costacc += __shfl_down(costacc, o, 64);
    if (lane == 0) redbuf[wv] = costacc;
    __syncthreads();
    if (tid == 0) {
        float s = redbuf[0] + redbuf[1] + redbuf[2] + redbuf[3];
        atomicAdd(cost, s * (1.0f / (float)((long)T_STEPS * BATCH * DOUT)));
    }
}

} // namespace

extern "C" void kernel_launch(void* const* d_in, const int* in_sizes, int n_in,
                              void* d_out, int out_size, void* d_ws, size_t ws_size,
                              hipStream_t stream) {
    const float* x      = (const float*)d_in[0];
    const float* y      = (const float*)d_in[1];
    const float* cmask  = (const float*)d_in[2];
    const float* weight = (const float*)d_in[3];
    const float* bias   = (const float*)d_in[4];
    const float* wout   = (const float*)d_in[5];
    const float* bout   = (const float*)d_in[6];

    float* yhat = (float*)d_out;
    float* cost = yhat + (size_t)T_STEPS * BATCH * DOUT;

    hipMemsetAsync(cost, 0, sizeof(float), stream);

    rnn_fused<<<dim3(NWG), dim3(NTHR), 0, stream>>>(
        x, y, cmask, weight, bias, wout, bout, yhat, cost);
}

// Round 3
// 3684.974 us; speedup vs baseline: 2.4584x; 1.2510x over previous
//
#include <hip/hip_runtime.h>

namespace {

constexpr int T_STEPS = 2000;
constexpr int BATCH   = 512;
constexpr int DIN     = 85;
constexpr int HID     = 256;
constexpr int DOUT    = 33;
constexpr int NWG     = 32;   // 16 batch rows per workgroup
constexpr int NTHR    = 256;  // 4 waves, 64 gate cols each

typedef float f32x4  __attribute__((ext_vector_type(4)));
typedef short bf16x8 __attribute__((ext_vector_type(8)));
typedef unsigned short ushort_t;

__device__ __forceinline__ short f2bf(float f) {
    union { float f; unsigned u; } v; v.f = f;
    unsigned r = v.u + 0x7fffu + ((v.u >> 16) & 1u);   // RNE
    return (short)(r >> 16);
}
__device__ __forceinline__ unsigned cvtpk(float lo, float hi) {
    unsigned r;
    asm("v_cvt_pk_bf16_f32 %0, %1, %2" : "=v"(r) : "v"(lo), "v"(hi));
    return r;
}
__device__ __forceinline__ float fast_rcp(float x) {
    float r; asm("v_rcp_f32 %0, %1" : "=v"(r) : "v"(x)); return r;
}
__device__ __forceinline__ float softplus_(float x) {
    float e = __expf(-fabsf(x));
    return fmaxf(x, 0.f) + __logf(1.f + e);
}
__device__ __forceinline__ float sigmoid_(float x) {
    return fast_rcp(1.f + __expf(-x));
}
// h K-slot permutation: slot(col) = (col&15)*16 + (col>>6)*4 + ((col>>4)&3)
__device__ __forceinline__ int kcol_of_slot(int s) {
    return ((s >> 2) & 3) * 64 + (s & 3) * 16 + (s >> 4);
}

// Barrier that drains ONLY lgkm (LDS) — global prefetch loads stay in flight.
// __syncthreads() would emit s_waitcnt vmcnt(0) and kill the x/y prefetch.
__device__ __forceinline__ void wg_barrier() {
    asm volatile("s_waitcnt lgkmcnt(0)" ::: "memory");
    __builtin_amdgcn_s_barrier();
    __builtin_amdgcn_sched_barrier(0);
}

#define MFMA16(a, b, c) __builtin_amdgcn_mfma_f32_16x16x32_bf16((a), (b), (c), 0, 0, 0)

__global__ __launch_bounds__(NTHR, 1) void rnn_fused(
    const float* __restrict__ x, const float* __restrict__ y,
    const float* __restrict__ cmask, const float* __restrict__ weight,
    const float* __restrict__ bias, const float* __restrict__ wout,
    const float* __restrict__ bout, float* __restrict__ yhat,
    float* __restrict__ cost)
{
    __shared__ __align__(16) ushort_t h_lds[2][16 * 256]; // 16 KB, swizzled
    __shared__ __align__(16) ushort_t x_lds[2][16 * 128]; // 8 KB, swizzled (k pad 85->96)
    __shared__ float redbuf[4];

    const int tid  = threadIdx.x;
    const int lane = tid & 63;
    const int wv   = tid >> 6;   // 0..3
    const int lg   = lane >> 4;  // 0..3
    const int li   = lane & 15;
    const int r0   = blockIdx.x * 16;

    // ---------------- weight fragments (registers; K permuted via slots) -------
    bf16x8 wrec[4][8], win[4][3];
    #pragma unroll
    for (int ct = 0; ct < 4; ++ct) {
        const int gcol = wv * 64 + ct * 16 + li;
        #pragma unroll
        for (int kk = 0; kk < 8; ++kk) {
            bf16x8 f;
            #pragma unroll
            for (int j = 0; j < 8; ++j) {
                const int kc = kcol_of_slot(32 * kk + 8 * lg + j);
                f[j] = f2bf(weight[(DIN + kc) * HID + gcol]);
            }
            wrec[ct][kk] = f;
        }
        #pragma unroll
        for (int kk = 0; kk < 3; ++kk) {
            bf16x8 f;
            #pragma unroll
            for (int j = 0; j < 8; ++j) {
                const int k = 32 * kk + 8 * lg + j;   // natural K for x
                f[j] = (k < DIN) ? f2bf(weight[k * HID + gcol]) : (short)0;
            }
            win[ct][kk] = f;
        }
    }
    float biasv[4];
    #pragma unroll
    for (int ct = 0; ct < 4; ++ct) biasv[ct] = bias[wv * 64 + ct * 16 + li];

    // projection fragments: waves 0..2 own col-tile wv (full K)
    const bool pw     = (wv < 3);
    const int  pcol   = wv * 16 + li;
    const bool pvalid = pw && (pcol < DOUT);
    bf16x8 wo[8];
    #pragma unroll
    for (int kk = 0; kk < 8; ++kk) {
        bf16x8 f;
        #pragma unroll
        for (int j = 0; j < 8; ++j) {
            const int kc = kcol_of_slot(32 * kk + 8 * lg + j);
            f[j] = pvalid ? f2bf(wout[kc * DOUT + pcol]) : (short)0;
        }
        wo[kk] = f;
    }
    const float bo = pvalid ? bout[pcol] : 0.f;
    int obase[4];
    #pragma unroll
    for (int r = 0; r < 4; ++r) obase[r] = (r0 + 4 * lg + r) * DOUT + pcol;

    // ---------------- LDS addresses (loop-invariant) ----------------
    const int swzli = (li & 7) << 4;
    int hA_off[8], xA_off[3], hW_off[4];
    #pragma unroll
    for (int kk = 0; kk < 8; ++kk) hA_off[kk] = li * 512 + ((kk * 64 + lg * 16) ^ swzli);
    #pragma unroll
    for (int kk = 0; kk < 3; ++kk) xA_off[kk] = li * 256 + ((kk * 64 + lg * 16) ^ swzli);
    #pragma unroll
    for (int r = 0; r < 4; ++r) {
        const int row = 4 * lg + r;
        hW_off[r] = row * 512 + ((li * 32 + wv * 8) ^ ((row & 7) << 4));
    }

    // x staging: 16 rows * 48 pairs = 768 pair-slots, 3 per thread
    int xg[3], xW_off[3]; bool v0[3], v1[3];
    #pragma unroll
    for (int i = 0; i < 3; ++i) {
        const int p   = tid + NTHR * i;
        const int row = p / 48;
        const int d0  = (p % 48) * 2;
        v0[i] = (d0 < DIN);
        v1[i] = (d0 + 1 < DIN);
        xg[i] = (r0 + row) * (T_STEPS * DIN) + d0;
        xW_off[i] = row * 256 + ((d0 * 2) ^ ((row & 7) << 4));
    }

    // ---------------- prologue ----------------
    // h(0) = 0
    for (int i = tid; i < 16 * 256; i += NTHR) h_lds[0][i] = 0;
    // stage x(0) into buffer 0
    #pragma unroll
    for (int i = 0; i < 3; ++i) {
        const float a = v0[i] ? x[xg[i]] : 0.f;
        const float b = v1[i] ? x[xg[i] + 1] : 0.f;
        *(unsigned*)((char*)x_lds[0] + xW_off[i]) = cvtpk(a, b);
    }
    // issue x(1) into regs (committed at iter 0)
    float xa[3], xb_[3];
    #pragma unroll
    for (int i = 0; i < 3; ++i) {
        xa[i]  = v0[i] ? x[xg[i] + DIN] : 0.f;
        xb_[i] = v1[i] ? x[xg[i] + DIN + 1] : 0.f;
    }
    __syncthreads();

    f32x4 hr[4] = {{0,0,0,0},{0,0,0,0},{0,0,0,0},{0,0,0,0}};
    f32x4 p0 = {0,0,0,0}, p1 = {0,0,0,0};
    float yv[4] = {0,0,0,0}, mv[4] = {0,0,0,0};
    int oidx[4] = {0,0,0,0};
    float costacc = 0.f;

    // ---------------- main sequential loop (one lgkm-only barrier/step) --------
    for (int t = 0; t < T_STEPS; ++t) {
        const int cur = t & 1, nxt = cur ^ 1;
        const char* hcur = (const char*)h_lds[cur];
        char*       hnxt = (char*)h_lds[nxt];
        const char* xcur = (const char*)x_lds[cur];
        char*       xnxt = (char*)x_lds[nxt];

        // (a) commit x(t+1) (loaded last iter; full-step latency already covered)
        if (t + 1 < T_STEPS) {
            #pragma unroll
            for (int i = 0; i < 3; ++i)
                *(unsigned*)(xnxt + xW_off[i]) = cvtpk(xa[i], xb_[i]);
        }

        // (b) issue all LDS reads for h(t), x(t)
        bf16x8 hA[8], xA[3];
        #pragma unroll
        for (int kk = 0; kk < 8; ++kk)
            hA[kk] = *(const bf16x8*)(hcur + hA_off[kk]);
        #pragma unroll
        for (int kk = 0; kk < 3; ++kk)
            xA[kk] = *(const bf16x8*)(xcur + xA_off[kk]);

        // (c) finalize yhat[t-2] (p0/p1 from last iter) — hides ds_read latency
        if (pvalid && t >= 2) {
            #pragma unroll
            for (int r = 0; r < 4; ++r) {
                const float s = sigmoid_(p0[r] + p1[r] + bo);
                yhat[oidx[r]] = s;
                const float d = (yv[r] - s) * mv[r];
                costacc += d * d;
            }
        }
        // (d) prefetch y/c_mask for output index t-1 (consumed next iter)
        if (pvalid && t >= 1) {
            #pragma unroll
            for (int r = 0; r < 4; ++r) {
                oidx[r] = (t - 1) * (BATCH * DOUT) + obase[r];
                yv[r] = y[oidx[r]];
                mv[r] = cmask[oidx[r]];
            }
        }
        // (e) issue x(t+2) loads (land any time before commit next iter)
        if (t + 2 < T_STEPS) {
            const int toff = (t + 2) * DIN;
            #pragma unroll
            for (int i = 0; i < 3; ++i) {
                xa[i]  = v0[i] ? x[xg[i] + toff] : 0.f;
                xb_[i] = v1[i] ? x[xg[i] + toff + 1] : 0.f;
            }
        }

        // (f) gate = h @ w_rec + x @ w_in + bias
        f32x4 acc[4];
        #pragma unroll
        for (int ct = 0; ct < 4; ++ct)
            acc[ct] = (f32x4){biasv[ct], biasv[ct], biasv[ct], biasv[ct]};
        #pragma unroll
        for (int kk = 0; kk < 8; ++kk) {
            const bf16x8 a = hA[kk];
            acc[0] = MFMA16(a, wrec[0][kk], acc[0]);
            acc[1] = MFMA16(a, wrec[1][kk], acc[1]);
            acc[2] = MFMA16(a, wrec[2][kk], acc[2]);
            acc[3] = MFMA16(a, wrec[3][kk], acc[3]);
        }
        #pragma unroll
        for (int kk = 0; kk < 3; ++kk) {
            const bf16x8 a = xA[kk];
            acc[0] = MFMA16(a, win[0][kk], acc[0]);
            acc[1] = MFMA16(a, win[1][kk], acc[1]);
            acc[2] = MFMA16(a, win[2][kk], acc[2]);
            acc[3] = MFMA16(a, win[3][kk], acc[3]);
        }

        // (g) projection of h(t) -> yhat[t-1] partials (reuses hA; off critical path)
        if (pw) {
            p0 = (f32x4){0,0,0,0}; p1 = (f32x4){0,0,0,0};
            #pragma unroll
            for (int kk = 0; kk < 4; ++kk) p0 = MFMA16(hA[kk], wo[kk], p0);
            #pragma unroll
            for (int kk = 4; kk < 8; ++kk) p1 = MFMA16(hA[kk], wo[kk], p1);
        }

        // (h) softplus + leaky update; pack -> b64 LDS write of h(t+1)
        #pragma unroll
        for (int r = 0; r < 4; ++r) {
            const float h0 = 0.8f * hr[0][r] + 0.2f * softplus_(acc[0][r]);
            const float h1 = 0.8f * hr[1][r] + 0.2f * softplus_(acc[1][r]);
            const float h2 = 0.8f * hr[2][r] + 0.2f * softplus_(acc[2][r]);
            const float h3 = 0.8f * hr[3][r] + 0.2f * softplus_(acc[3][r]);
            hr[0][r] = h0; hr[1][r] = h1; hr[2][r] = h2; hr[3][r] = h3;
            uint2 pk; pk.x = cvtpk(h0, h1); pk.y = cvtpk(h2, h3);
            *(uint2*)(hnxt + hW_off[r]) = pk;
        }

        // (i) lgkm-only barrier: h(t+1)/x(t+1) visible, vm prefetch stays in flight
        wg_barrier();
    }

    // ---------------- epilogue ----------------
    // finalize yhat[T-2] (p0/p1, y/mv from iter T-1)
    if (pvalid) {
        #pragma unroll
        for (int r = 0; r < 4; ++r) {
            const float s = sigmoid_(p0[r] + p1[r] + bo);
            yhat[oidx[r]] = s;
            const float d = (yv[r] - s) * mv[r];
            costacc += d * d;
        }
    }
    // project h(T) -> yhat[T-1]
    {
        const char* hfin = (const char*)h_lds[T_STEPS & 1];
        if (pw) {
            p0 = (f32x4){0,0,0,0}; p1 = (f32x4){0,0,0,0};
            #pragma unroll
            for (int kk = 0; kk < 8; ++kk) {
                const bf16x8 a = *(const bf16x8*)(hfin + hA_off[kk]);
                if (kk < 4) p0 = MFMA16(a, wo[kk], p0);
                else        p1 = MFMA16(a, wo[kk], p1);
            }
        }
        if (pvalid) {
            #pragma unroll
            for (int r = 0; r < 4; ++r) {
                const int idx = (T_STEPS - 1) * (BATCH * DOUT) + obase[r];
                const float s = sigmoid_(p0[r] + p1[r] + bo);
                yhat[idx] = s;
                const float d = (y[idx] - s) * cmask[idx];
                costacc += d * d;
            }
        }
    }

    // ---------------- cost reduction ----------------
    #pragma unroll
    for (int o = 32; o > 0; o >>= 1)
        costacc += __shfl_down(costacc, o, 64);
    if (lane == 0) redbuf[wv] = costacc;
    __syncthreads();
    if (tid == 0) {
        float s = redbuf[0] + redbuf[1] + redbuf[2] + redbuf[3];
        atomicAdd(cost, s * (1.0f / (float)((long)T_STEPS * BATCH * DOUT)));
    }
}

} // namespace

extern "C" void kernel_launch(void* const* d_in, const int* in_sizes, int n_in,
                              void* d_out, int out_size, void* d_ws, size_t ws_size,
                              hipStream_t stream) {
    const float* x      = (const float*)d_in[0];
    const float* y      = (const float*)d_in[1];
    const float* cmask  = (const float*)d_in[2];
    const float* weight = (const float*)d_in[3];
    const float* bias   = (const float*)d_in[4];
    const float* wout   = (const float*)d_in[5];
    const float* bout   = (const float*)d_in[6];

    float* yhat = (float*)d_out;
    float* cost = yhat + (size_t)T_STEPS * BATCH * DOUT;

    hipMemsetAsync(cost, 0, sizeof(float), stream);

    rnn_fused<<<dim3(NWG), dim3(NTHR), 0, stream>>>(
        x, y, cmask, weight, bias, wout, bout, yhat, cost);
}

// Round 4
// 3228.821 us; speedup vs baseline: 2.8057x; 1.1413x over previous
//
#include <hip/hip_runtime.h>

namespace {

constexpr int T_STEPS = 2000;
constexpr int BATCH   = 512;
constexpr int DIN     = 85;
constexpr int HID     = 256;
constexpr int DOUT    = 33;
constexpr int NWG     = 32;   // 16 batch rows per workgroup
constexpr int NTHR    = 512;  // 8 waves: 0-3 gate (G), 4-7 aux (P); 2 waves/SIMD

typedef float f32x4  __attribute__((ext_vector_type(4)));
typedef short bf16x8 __attribute__((ext_vector_type(8)));
typedef unsigned short ushort_t;

__device__ __forceinline__ short f2bf(float f) {
    union { float f; unsigned u; } v; v.f = f;
    unsigned r = v.u + 0x7fffu + ((v.u >> 16) & 1u);   // RNE
    return (short)(r >> 16);
}
__device__ __forceinline__ unsigned cvtpk(float lo, float hi) {
    unsigned r;
    asm("v_cvt_pk_bf16_f32 %0, %1, %2" : "=v"(r) : "v"(lo), "v"(hi));
    return r;
}
__device__ __forceinline__ float fast_rcp(float x) {
    float r; asm("v_rcp_f32 %0, %1" : "=v"(r) : "v"(x)); return r;
}
__device__ __forceinline__ float softplus_(float x) {
    float e = __expf(-fabsf(x));
    return fmaxf(x, 0.f) + __logf(1.f + e);
}
__device__ __forceinline__ float sigmoid_(float x) {
    return fast_rcp(1.f + __expf(-x));
}
// h K-slot permutation chosen so the h-WRITE is bank-conflict-free:
// slot(col) = (col>>6)*64 + (col&15)*4 + ((col>>4)&3)
// inverse:
__device__ __forceinline__ int kcol_of_slot(int s) {
    return (s & 192) + ((s & 3) << 4) + ((s >> 2) & 15);
}
// Barrier draining ONLY lgkm (LDS); global prefetch loads stay in flight.
__device__ __forceinline__ void wg_barrier() {
    asm volatile("s_waitcnt lgkmcnt(0)" ::: "memory");
    __builtin_amdgcn_s_barrier();
    __builtin_amdgcn_sched_barrier(0);
}

#define MFMA16(a, b, c) __builtin_amdgcn_mfma_f32_16x16x32_bf16((a), (b), (c), 0, 0, 0)

__global__ __launch_bounds__(NTHR) void rnn_fused(
    const float* __restrict__ x, const float* __restrict__ y,
    const float* __restrict__ cmask, const float* __restrict__ weight,
    const float* __restrict__ bias, const float* __restrict__ wout,
    const float* __restrict__ bout, float* __restrict__ yhat,
    float* __restrict__ cost)
{
    // h: [buf][row 16][slot 256] bf16, 512 B/row, XOR-swizzled (slots = permuted cols)
    // xacc: [buf][col 256][row 16] f32, 64 B/col, XOR-swizzled (x@W_in + bias, C-layout)
    // x: [buf][row 16][slot 128] bf16, 256 B/row, XOR-swizzled (natural K, pad 85->96)
    __shared__ __align__(16) ushort_t h_lds[2][16 * 256];    // 16 KB
    __shared__ __align__(16) float    xacc_lds[2][256 * 16]; // 32 KB
    __shared__ __align__(16) ushort_t x_lds[2][16 * 128];    // 8 KB
    __shared__ float redbuf[8];

    const int tid  = threadIdx.x;
    const int lane = tid & 63;
    const int wv   = tid >> 6;   // 0..7
    const int lg   = lane >> 4;  // 0..3
    const int li   = lane & 15;
    const int r0   = blockIdx.x * 16;
    const bool isG = (wv < 4);
    const int  m   = isG ? wv : (wv - 4);  // column-group 0..3
    const int  cw  = m * 64;

    float costacc = 0.f;

    // ---- shared loop-invariant LDS byte offsets ----
    int hA_off[8];
    #pragma unroll
    for (int kk = 0; kk < 8; ++kk)
        hA_off[kk] = li * 512 + ((kk * 64 + lg * 16) ^ ((li & 7) << 4));
    int cA_off[4];   // xacc f32x4 (seed read on G / partial write on P)
    #pragma unroll
    for (int ct = 0; ct < 4; ++ct)
        cA_off[ct] = (cw + ct * 16 + li) * 64 + ((lg * 16) ^ ((li & 3) << 4));

    if (isG) {
        // ================= gate waves: h-recurrence only =================
        {   // zero h(0)
            uint4* hz = (uint4*)&h_lds[0][0];
            hz[tid]       = uint4{0, 0, 0, 0};
            hz[tid + 256] = uint4{0, 0, 0, 0};
        }
        // w_rec fragments (registers; K permuted via slots)
        bf16x8 wrec[4][8];
        #pragma unroll
        for (int ct = 0; ct < 4; ++ct) {
            const int gcol = cw + ct * 16 + li;
            #pragma unroll
            for (int kk = 0; kk < 8; ++kk) {
                bf16x8 f;
                #pragma unroll
                for (int j = 0; j < 8; ++j)
                    f[j] = f2bf(weight[(DIN + kcol_of_slot(32 * kk + 8 * lg + j)) * HID + gcol]);
                wrec[ct][kk] = f;
            }
        }
        // conflict-free h-write offsets: lane's 4 ct-values at slots m*64+li*4+{0..3}
        int hW_off[4];
        #pragma unroll
        for (int r = 0; r < 4; ++r) {
            const int row = 4 * lg + r;
            hW_off[r] = row * 512 + ((m * 128 + li * 8) ^ ((row & 7) << 4));
        }

        __syncthreads();   // (1) P staged x(0)/x(1)
        __syncthreads();   // (2) P wrote xacc(0)

        f32x4 hr[4] = {{0,0,0,0},{0,0,0,0},{0,0,0,0},{0,0,0,0}};

        for (int t = 0; t < T_STEPS; ++t) {
            const char* hcur = (const char*)&h_lds[t & 1][0];
            char*       hnxt = (char*)&h_lds[(t + 1) & 1][0];
            const char* xac  = (const char*)&xacc_lds[t & 1][0];

            // accumulator init = precomputed bias + x(t)@W_in (from P waves)
            f32x4 acc[4];
            #pragma unroll
            for (int ct = 0; ct < 4; ++ct)
                acc[ct] = *(const f32x4*)(xac + cA_off[ct]);
            bf16x8 hA[8];
            #pragma unroll
            for (int kk = 0; kk < 8; ++kk)
                hA[kk] = *(const bf16x8*)(hcur + hA_off[kk]);
            #pragma unroll
            for (int kk = 0; kk < 8; ++kk) {
                const bf16x8 a = hA[kk];
                acc[0] = MFMA16(a, wrec[0][kk], acc[0]);
                acc[1] = MFMA16(a, wrec[1][kk], acc[1]);
                acc[2] = MFMA16(a, wrec[2][kk], acc[2]);
                acc[3] = MFMA16(a, wrec[3][kk], acc[3]);
            }
            // leaky softplus update; 4 ct-values -> consecutive slots -> b64 write
            #pragma unroll
            for (int r = 0; r < 4; ++r) {
                const float h0 = 0.8f * hr[0][r] + 0.2f * softplus_(acc[0][r]);
                const float h1 = 0.8f * hr[1][r] + 0.2f * softplus_(acc[1][r]);
                const float h2 = 0.8f * hr[2][r] + 0.2f * softplus_(acc[2][r]);
                const float h3 = 0.8f * hr[3][r] + 0.2f * softplus_(acc[3][r]);
                hr[0][r] = h0; hr[1][r] = h1; hr[2][r] = h2; hr[3][r] = h3;
                uint2 pk; pk.x = cvtpk(h0, h1); pk.y = cvtpk(h2, h3);
                *(uint2*)(hnxt + hW_off[r]) = pk;
            }
            wg_barrier();
        }
    } else {
        // ====== aux waves: x-projection pipeline + output proj + finalize ======
        bf16x8 win[4][3];
        float biasv[4];
        #pragma unroll
        for (int ct = 0; ct < 4; ++ct) {
            const int gcol = cw + ct * 16 + li;
            biasv[ct] = bias[gcol];
            #pragma unroll
            for (int kk = 0; kk < 3; ++kk) {
                bf16x8 f;
                #pragma unroll
                for (int j = 0; j < 8; ++j) {
                    const int k = 32 * kk + 8 * lg + j;   // natural K for x
                    f[j] = (k < DIN) ? f2bf(weight[k * HID + gcol]) : (short)0;
                }
                win[ct][kk] = f;
            }
        }
        const bool pw     = (wv < 7);
        const int  pcol   = (wv - 4) * 16 + li;
        const bool pvalid = pw && (pcol < DOUT);
        bf16x8 wo[8];
        #pragma unroll
        for (int kk = 0; kk < 8; ++kk) {
            bf16x8 f;
            #pragma unroll
            for (int j = 0; j < 8; ++j)
                f[j] = pvalid ? f2bf(wout[kcol_of_slot(32 * kk + 8 * lg + j) * DOUT + pcol])
                              : (short)0;
            wo[kk] = f;
        }
        const float bo = pvalid ? bout[pcol] : 0.f;
        int obase[4];
        #pragma unroll
        for (int r = 0; r < 4; ++r) obase[r] = (r0 + 4 * lg + r) * DOUT + pcol;

        // x staging: 768 pair-slots over 256 P-lanes, 3 each
        const int ptid = tid - 256;
        int xg[3], xW_off[3]; bool v0[3], v1[3];
        #pragma unroll
        for (int i = 0; i < 3; ++i) {
            const int p   = ptid + 256 * i;
            const int row = p / 48;
            const int d0  = (p % 48) * 2;
            v0[i] = (d0 < DIN); v1[i] = (d0 + 1 < DIN);
            xg[i] = (r0 + row) * (T_STEPS * DIN) + d0;
            xW_off[i] = row * 256 + ((d0 * 2) ^ ((row & 7) << 4));
        }
        int xA_off[3];
        #pragma unroll
        for (int kk = 0; kk < 3; ++kk)
            xA_off[kk] = li * 256 + ((kk * 64 + lg * 16) ^ ((li & 7) << 4));

        // prologue: stage x(0)->buf0, x(1)->buf1; issue x(2) into regs
        #pragma unroll
        for (int i = 0; i < 3; ++i) {
            const float a0 = v0[i] ? x[xg[i]] : 0.f;
            const float b0 = v1[i] ? x[xg[i] + 1] : 0.f;
            *(unsigned*)((char*)&x_lds[0][0] + xW_off[i]) = cvtpk(a0, b0);
            const float a1 = v0[i] ? x[xg[i] + DIN] : 0.f;
            const float b1 = v1[i] ? x[xg[i] + DIN + 1] : 0.f;
            *(unsigned*)((char*)&x_lds[1][0] + xW_off[i]) = cvtpk(a1, b1);
        }
        float xa[3], xb[3];
        #pragma unroll
        for (int i = 0; i < 3; ++i) {
            xa[i] = v0[i] ? x[xg[i] + 2 * DIN] : 0.f;
            xb[i] = v1[i] ? x[xg[i] + 2 * DIN + 1] : 0.f;
        }
        __syncthreads();   // (1) x(0)/x(1) visible
        {   // xacc(0) = bias + x(0)@W_in
            f32x4 xc[4];
            #pragma unroll
            for (int ct = 0; ct < 4; ++ct)
                xc[ct] = (f32x4){biasv[ct], biasv[ct], biasv[ct], biasv[ct]};
            #pragma unroll
            for (int kk = 0; kk < 3; ++kk) {
                const bf16x8 a = *(const bf16x8*)((const char*)&x_lds[0][0] + xA_off[kk]);
                xc[0] = MFMA16(a, win[0][kk], xc[0]);
                xc[1] = MFMA16(a, win[1][kk], xc[1]);
                xc[2] = MFMA16(a, win[2][kk], xc[2]);
                xc[3] = MFMA16(a, win[3][kk], xc[3]);
            }
            char* xad = (char*)&xacc_lds[0][0];
            #pragma unroll
            for (int ct = 0; ct < 4; ++ct)
                *(f32x4*)(xad + cA_off[ct]) = xc[ct];
        }
        __syncthreads();   // (2) xacc(0) visible

        f32x4 p0 = {0,0,0,0}, p1 = {0,0,0,0};
        float yv[4] = {0,0,0,0}, mv[4] = {0,0,0,0};
        int oidx[4] = {0,0,0,0};

        for (int t = 0; t < T_STEPS; ++t) {
            // (a) finalize yhat[t-2] (p from iter t-1) — off G's critical path
            if (pvalid && t >= 2) {
                #pragma unroll
                for (int r = 0; r < 4; ++r) {
                    const float s = sigmoid_(p0[r] + p1[r] + bo);
                    yhat[oidx[r]] = s;
                    const float d = (yv[r] - s) * mv[r];
                    costacc += d * d;
                }
            }
            // (b) prefetch y/c_mask for output t-1 (consumed next iter)
            if (pvalid && t >= 1) {
                #pragma unroll
                for (int r = 0; r < 4; ++r) {
                    oidx[r] = (t - 1) * (BATCH * DOUT) + obase[r];
                    yv[r] = y[oidx[r]];
                    mv[r] = cmask[oidx[r]];
                }
            }
            // (c) commit x(t+2) (loaded iter t-1; >1 step of HBM latency covered)
            if (t + 2 < T_STEPS) {
                char* xnb = (char*)&x_lds[t & 1][0];
                #pragma unroll
                for (int i = 0; i < 3; ++i)
                    *(unsigned*)(xnb + xW_off[i]) = cvtpk(xa[i], xb[i]);
            }
            // (d) issue x(t+3) loads
            if (t + 3 < T_STEPS) {
                const int toff = (t + 3) * DIN;
                #pragma unroll
                for (int i = 0; i < 3; ++i) {
                    xa[i] = v0[i] ? x[xg[i] + toff] : 0.f;
                    xb[i] = v1[i] ? x[xg[i] + toff + 1] : 0.f;
                }
            }
            // (e) xacc(t+1) = bias + x(t+1)@W_in  -> seeds G's gate next iter
            if (t + 1 < T_STEPS) {
                const char* xbuf = (const char*)&x_lds[(t + 1) & 1][0];
                f32x4 xc[4];
                #pragma unroll
                for (int ct = 0; ct < 4; ++ct)
                    xc[ct] = (f32x4){biasv[ct], biasv[ct], biasv[ct], biasv[ct]};
                #pragma unroll
                for (int kk = 0; kk < 3; ++kk) {
                    const bf16x8 a = *(const bf16x8*)(xbuf + xA_off[kk]);
                    xc[0] = MFMA16(a, win[0][kk], xc[0]);
                    xc[1] = MFMA16(a, win[1][kk], xc[1]);
                    xc[2] = MFMA16(a, win[2][kk], xc[2]);
                    xc[3] = MFMA16(a, win[3][kk], xc[3]);
                }
                char* xad = (char*)&xacc_lds[(t + 1) & 1][0];
                #pragma unroll
                for (int ct = 0; ct < 4; ++ct)
                    *(f32x4*)(xad + cA_off[ct]) = xc[ct];
            }
            // (f) projection of h(t) -> yhat[t-1] partials (waves 4..6)
            if (pw) {
                const char* hcur = (const char*)&h_lds[t & 1][0];
                bf16x8 hA[8];
                #pragma unroll
                for (int kk = 0; kk < 8; ++kk)
                    hA[kk] = *(const bf16x8*)(hcur + hA_off[kk]);
                p0 = (f32x4){0,0,0,0}; p1 = (f32x4){0,0,0,0};
                #pragma unroll
                for (int kk = 0; kk < 4; ++kk) p0 = MFMA16(hA[kk], wo[kk], p0);
                #pragma unroll
                for (int kk = 4; kk < 8; ++kk) p1 = MFMA16(hA[kk], wo[kk], p1);
            }
            wg_barrier();
        }

        // ---- epilogue ----
        if (pvalid) {   // finalize yhat[T-2]
            #pragma unroll
            for (int r = 0; r < 4; ++r) {
                const float s = sigmoid_(p0[r] + p1[r] + bo);
                yhat[oidx[r]] = s;
                const float d = (yv[r] - s) * mv[r];
                costacc += d * d;
            }
        }
        if (pw) {       // project h(T) -> yhat[T-1]
            const char* hfin = (const char*)&h_lds[T_STEPS & 1][0];
            p0 = (f32x4){0,0,0,0}; p1 = (f32x4){0,0,0,0};
            #pragma unroll
            for (int kk = 0; kk < 8; ++kk) {
                const bf16x8 a = *(const bf16x8*)(hfin + hA_off[kk]);
                if (kk < 4) p0 = MFMA16(a, wo[kk], p0);
                else        p1 = MFMA16(a, wo[kk], p1);
            }
            if (pvalid) {
                #pragma unroll
                for (int r = 0; r < 4; ++r) {
                    const int idx = (T_STEPS - 1) * (BATCH * DOUT) + obase[r];
                    const float s = sigmoid_(p0[r] + p1[r] + bo);
                    yhat[idx] = s;
                    const float d = (y[idx] - s) * cmask[idx];
                    costacc += d * d;
                }
            }
        }
    }

    // ---------------- cost reduction ----------------
    #pragma unroll
    for (int o = 32; o > 0; o >>= 1)
        costacc += __shfl_down(costacc, o, 64);
    if (lane == 0) redbuf[wv] = costacc;
    __syncthreads();
    if (tid == 0) {
        float s = 0.f;
        #pragma unroll
        for (int i = 0; i < 8; ++i) s += redbuf[i];
        atomicAdd(cost, s * (1.0f / (float)((long)T_STEPS * BATCH * DOUT)));
    }
}

} // namespace

extern "C" void kernel_launch(void* const* d_in, const int* in_sizes, int n_in,
                              void* d_out, int out_size, void* d_ws, size_t ws_size,
                              hipStream_t stream) {
    const float* x      = (const float*)d_in[0];
    const float* y      = (const float*)d_in[1];
    const float* cmask  = (const float*)d_in[2];
    const float* weight = (const float*)d_in[3];
    const float* bias   = (const float*)d_in[4];
    const float* wout   = (const float*)d_in[5];
    const float* bout   = (const float*)d_in[6];

    float* yhat = (float*)d_out;
    float* cost = yhat + (size_t)T_STEPS * BATCH * DOUT;

    hipMemsetAsync(cost, 0, sizeof(float), stream);

    rnn_fused<<<dim3(NWG), dim3(NTHR), 0, stream>>>(
        x, y, cmask, weight, bias, wout, bout, yhat, cost);
}